// Round 9
// baseline (517.220 us; speedup 1.0000x reference)
//
#include <hip/hip_runtime.h>

typedef short bf16x8 __attribute__((ext_vector_type(8)));
typedef float f32x4  __attribute__((ext_vector_type(4)));
typedef unsigned int u32;
typedef unsigned short u16;

#define NBATCH 16
#define C      512
#define NPIX   4096
#define ATT_OFF ((size_t)NBATCH * 1024 * NPIX)   // 67,108,864 floats

typedef __attribute__((address_space(1))) const u32* gp_t;
typedef __attribute__((address_space(3))) u32* lp_t;

// split one f32 pair (raw bits) -> packed bf16 hi pair + bf16 lo pair
__device__ __forceinline__ void splitpair(u32 u0, u32 u1, u32& h, u32& l) {
    h = __builtin_amdgcn_perm(u1, u0, 0x07060302u);
    const u32 m0 = u0 & 0xFFFF0000u, m1 = u1 & 0xFFFF0000u;
    const float l0 = __uint_as_float(u0) - __uint_as_float(m0);
    const float l1 = __uint_as_float(u1) - __uint_as_float(m1);
    l = __builtin_amdgcn_perm(__float_as_uint(l1), __float_as_uint(l0), 0x07060302u);
}

// ---------------------------------------------------------------------------
// GEMM1: energy[b,i,j] = sum_n x1[b,i,n]*x2[b,j,n]  (split-bf16, 3 MFMA)
// 1024 blocks = split-K=4, 4 blocks/CU (16 waves/CU) — TLP hides the
// per-block barrier drains (m114 cross-block overlap). Single-buffer
// 32KB f32 LDS staged via global_load_lds DMA; split-to-bf16 after
// ds_read, ordered BEFORE barrier#2 to keep VGPR live-range < 128.
// ks=0 partial -> att slot; ks=1..3 parked in av region (gemm2 overwrites).
// ---------------------------------------------------------------------------
__global__ __launch_bounds__(256, 4) void gemm1_energy(
    const float* __restrict__ x1, const float* __restrict__ x2,
    float* __restrict__ out)
{
    __shared__ __align__(16) float Asm[128 * 32];
    __shared__ __align__(16) float Bsm[128 * 32];

    const int tid  = threadIdx.x;
    const int lane = tid & 63;
    const int w    = tid >> 6;
    const int wr   = (w >> 1) * 64;
    const int wc   = (w & 1) * 64;
    const int r16  = lane & 15;
    const int g    = lane >> 4;

    const int gid = (blockIdx.x & 7) * 128 + (blockIdx.x >> 3);  // XCD swizzle (1024%8==0)
    const int jb  = (gid & 3) * 128;
    const int ib  = ((gid >> 2) & 3) * 128;
    const int b   = (gid >> 4) & 15;
    const int ks  = gid >> 8;            // 0..3
    const int ko  = ks * 1024;

    // staging source pointers: issue q covers tile rows w*32+q*8 .. +8
    const int lrow  = lane >> 3;        // 0..7
    const int chunk = lane & 7;         // 16B chunk within 128B row window
    const float* srcA[4];
    const float* srcB[4];
    #pragma unroll
    for (int q = 0; q < 4; ++q) {
        const int row = w * 32 + q * 8 + lrow;
        const int sc  = (chunk ^ ((row >> 1) & 7)) * 4;   // source pre-swizzle
        srcA[q] = x1 + (size_t)(b * C + ib + row) * NPIX + ko + sc;
        srcB[q] = x2 + (size_t)(b * C + jb + row) * NPIX + ko + sc;
    }

    auto stage = [&](int kt) {            // 8 global_load_lds per thread
        #pragma unroll
        for (int q = 0; q < 4; ++q) {
            __builtin_amdgcn_global_load_lds((gp_t)(const void*)(srcA[q] + kt * 32),
                                             (lp_t)(void*)&Asm[(w * 32 + q * 8) * 32], 16, 0, 0);
            __builtin_amdgcn_global_load_lds((gp_t)(const void*)(srcB[q] + kt * 32),
                                             (lp_t)(void*)&Bsm[(w * 32 + q * 8) * 32], 16, 0, 0);
        }
    };

    const f32x4 zero4 = {0.f, 0.f, 0.f, 0.f};
    f32x4 acc[4][4];
    #pragma unroll
    for (int i = 0; i < 4; ++i)
        #pragma unroll
        for (int j = 0; j < 4; ++j) acc[i][j] = zero4;

    union B8 { bf16x8 v; u32 u[4]; };

    stage(0);

    for (int kt = 0; kt < 32; ++kt) {
        __syncthreads();                  // stage(kt) landed (drains vmcnt)

        uint4 UA[4][2], UB[4][2];
        #pragma unroll
        for (int f = 0; f < 4; ++f) {
            const int ar = wr + f * 16 + r16;
            const float* abase = &Asm[ar * 32];
            UA[f][0] = *(const uint4*)(abase + (((2 * g)     ^ ((ar >> 1) & 7)) * 4));
            UA[f][1] = *(const uint4*)(abase + (((2 * g + 1) ^ ((ar >> 1) & 7)) * 4));
            const int br = wc + f * 16 + r16;
            const float* bbase = &Bsm[br * 32];
            UB[f][0] = *(const uint4*)(bbase + (((2 * g)     ^ ((br >> 1) & 7)) * 4));
            UB[f][1] = *(const uint4*)(bbase + (((2 * g + 1) ^ ((br >> 1) & 7)) * 4));
        }

        // split BEFORE barrier#2: UA/UB die here, only ah..bl (32) + acc live
        B8 ah[4], al[4], bh[4], bl[4];
        #pragma unroll
        for (int f = 0; f < 4; ++f) {
            splitpair(UA[f][0].x, UA[f][0].y, ah[f].u[0], al[f].u[0]);
            splitpair(UA[f][0].z, UA[f][0].w, ah[f].u[1], al[f].u[1]);
            splitpair(UA[f][1].x, UA[f][1].y, ah[f].u[2], al[f].u[2]);
            splitpair(UA[f][1].z, UA[f][1].w, ah[f].u[3], al[f].u[3]);
            splitpair(UB[f][0].x, UB[f][0].y, bh[f].u[0], bl[f].u[0]);
            splitpair(UB[f][0].z, UB[f][0].w, bh[f].u[1], bl[f].u[1]);
            splitpair(UB[f][1].x, UB[f][1].y, bh[f].u[2], bl[f].u[2]);
            splitpair(UB[f][1].z, UB[f][1].w, bh[f].u[3], bl[f].u[3]);
        }

        __syncthreads();                  // all waves consumed LDS (lgkm drained)
        if (kt + 1 < 32) stage(kt + 1);   // overwrite LDS; flies during MFMA

        __builtin_amdgcn_s_setprio(1);
        #pragma unroll
        for (int fi = 0; fi < 4; ++fi)
            #pragma unroll
            for (int fj = 0; fj < 4; ++fj) {
                acc[fi][fj] = __builtin_amdgcn_mfma_f32_16x16x32_bf16(ah[fi].v, bh[fj].v, acc[fi][fj], 0, 0, 0);
                acc[fi][fj] = __builtin_amdgcn_mfma_f32_16x16x32_bf16(ah[fi].v, bl[fj].v, acc[fi][fj], 0, 0, 0);
                acc[fi][fj] = __builtin_amdgcn_mfma_f32_16x16x32_bf16(al[fi].v, bh[fj].v, acc[fi][fj], 0, 0, 0);
            }
        __builtin_amdgcn_s_setprio(0);
    }

    // partial energies: ks=0 -> att slot; ks>=1 -> park in av region
    float* dst = (ks == 0)
        ? (out + ATT_OFF + (size_t)b * C * C)
        : (out + (size_t)(b * 1024 + 512) * NPIX + (size_t)(ks - 1) * C * C);
    #pragma unroll
    for (int fi = 0; fi < 4; ++fi)
        #pragma unroll
        for (int fj = 0; fj < 4; ++fj) {
            const int j = jb + wc + fj * 16 + r16;
            #pragma unroll
            for (int q = 0; q < 4; ++q) {
                const int i = ib + wr + fi * 16 + g * 4 + q;
                dst[(size_t)i * C + j] = acc[fi][fj][q];
            }
        }
}

// ---------------------------------------------------------------------------
// Softmax over last dim (512): sums the 4 split-K partials, softmaxes,
// writes final attention into the att slot.
// ---------------------------------------------------------------------------
__global__ __launch_bounds__(256) void softmax_rows(float* __restrict__ out)
{
    const int bi = blockIdx.x;          // b*512 + i
    const int b  = bi >> 9;
    const int i  = bi & 511;
    float* p        = out + ATT_OFF + (size_t)bi * C;
    const float* pk = out + (size_t)(b * 1024 + 512) * NPIX + (size_t)i * C;

    const int t = threadIdx.x;
    const int lane = t & 63, wid = t >> 6;
    __shared__ float red[8];

    float a = p[t]       + pk[t]                 + pk[C * C + t]       + pk[2 * C * C + t];
    float c = p[t + 256] + pk[t + 256] + pk[C * C + t + 256] + pk[2 * C * C + t + 256];
    float m = fmaxf(a, c);
    #pragma unroll
    for (int o = 32; o; o >>= 1) m = fmaxf(m, __shfl_xor(m, o));
    if (lane == 0) red[wid] = m;
    __syncthreads();
    m = fmaxf(fmaxf(red[0], red[1]), fmaxf(red[2], red[3]));

    float e0 = __expf(a - m), e1 = __expf(c - m);
    float s = e0 + e1;
    #pragma unroll
    for (int o = 32; o; o >>= 1) s += __shfl_xor(s, o);
    if (lane == 0) red[4 + wid] = s;
    __syncthreads();
    s = (red[4] + red[5]) + (red[6] + red[7]);
    const float inv = 1.0f / s;
    p[t]       = e0 * inv;
    p[t + 256] = e1 * inv;
}

// ---------------------------------------------------------------------------
// GEMM2: av[b,j,n] = sum_k att[b,k,j] * x1[b,k,n]   (TT, K=512, bf16 MFMA)
// Deferred pack (T14). jt fastest in gid so the 4 blocks sharing an x1
// n-panel are dispatch-adjacent on the same XCD -> L2 absorbs re-reads.
// jt==0 blocks also copy their staged x1 f32 tile to out channels [0,512).
// ---------------------------------------------------------------------------
#define KST 36   // u16 stride per LDS row (32 + 4 pad)

__global__ __launch_bounds__(256, 3) void gemm2_av(
    const float* __restrict__ x1, float* __restrict__ out)
{
    __shared__ __align__(16) u16 Aj[2][128 * KST];  // att^T tile: row j, k 0..31
    __shared__ __align__(16) u16 Bn[2][128 * KST];  // x1^T tile: row n, k 0..31

    const float* att = out + ATT_OFF;
    const int tid  = threadIdx.x;
    const int lane = tid & 63;
    const int wid  = tid >> 6;
    const int wr   = (wid >> 1) * 64;   // j
    const int wc   = (wid & 1) * 64;    // n
    const int r16  = lane & 15;
    const int g    = lane >> 4;

    const int gid = (blockIdx.x & 7) * 256 + (blockIdx.x >> 3);  // XCD swizzle
    const int jt  = gid & 3;            // fastest: same-panel blocks adjacent
    const int nt  = (gid >> 2) & 31;
    const int b   = gid >> 7;
    const int jb  = jt * 128;
    const int nb  = nt * 128;

    const int col = (tid & 31) * 4;     // j (or n) column group staged
    const int ksr = (tid >> 5) * 4;     // 4 k's per thread per tile

    const float* ap0 = att + (size_t)b * C * C    + (size_t)ksr * C    + jb + col;
    const float* bp0 = x1  + (size_t)b * C * NPIX + (size_t)ksr * NPIX + nb + col;
    float* cpy = out + (size_t)(b * 1024 + ksr) * NPIX + nb + col;

    f32x4 La[4], Lb[4];

    auto loadk = [&](int kt) {
        #pragma unroll
        for (int i = 0; i < 4; ++i) {
            La[i] = *(const f32x4*)(ap0 + (size_t)(kt * 32 + i) * C);
            Lb[i] = *(const f32x4*)(bp0 + (size_t)(kt * 32 + i) * NPIX);
        }
    };

    auto stage = [&](int kt, int buf) {
        u32 sa[8], sb[8];
        #pragma unroll
        for (int jj = 0; jj < 4; ++jj) {
            sa[jj * 2]     = __builtin_amdgcn_perm(__float_as_uint(La[1][jj]), __float_as_uint(La[0][jj]), 0x07060302u);
            sa[jj * 2 + 1] = __builtin_amdgcn_perm(__float_as_uint(La[3][jj]), __float_as_uint(La[2][jj]), 0x07060302u);
            sb[jj * 2]     = __builtin_amdgcn_perm(__float_as_uint(Lb[1][jj]), __float_as_uint(Lb[0][jj]), 0x07060302u);
            sb[jj * 2 + 1] = __builtin_amdgcn_perm(__float_as_uint(Lb[3][jj]), __float_as_uint(Lb[2][jj]), 0x07060302u);
        }
        #pragma unroll
        for (int jj = 0; jj < 4; ++jj) {
            *(uint2*)((char*)Aj[buf] + ((col + jj) * KST + ksr) * 2) = make_uint2(sa[jj * 2], sa[jj * 2 + 1]);
            *(uint2*)((char*)Bn[buf] + ((col + jj) * KST + ksr) * 2) = make_uint2(sb[jj * 2], sb[jj * 2 + 1]);
        }
        if (jt == 0) {                  // fused x1 -> out copy
            #pragma unroll
            for (int i = 0; i < 4; ++i)
                *(f32x4*)(cpy + (size_t)(kt * 32 + i) * NPIX) = Lb[i];
        }
    };

    const f32x4 zero4 = {0.f, 0.f, 0.f, 0.f};
    f32x4 acc[4][4];
    #pragma unroll
    for (int i = 0; i < 4; ++i)
        #pragma unroll
        for (int j = 0; j < 4; ++j) acc[i][j] = zero4;

    loadk(0);
    stage(0, 0);

    for (int kt = 0; kt < 16; ++kt) {
        if (kt < 15) loadk(kt + 1);     // raw loads issued early (T14)
        __syncthreads();
        const int buf = kt & 1;

        union { bf16x8 v; uint2 u2[2]; } fa[4], fb[4];
        #pragma unroll
        for (int f = 0; f < 4; ++f) {
            const int aj = wr + f * 16 + r16;
            fa[f].u2[0] = *(const uint2*)(&Aj[buf][aj * KST + g * 8]);
            fa[f].u2[1] = *(const uint2*)(&Aj[buf][aj * KST + g * 8 + 4]);
            const int bn = wc + f * 16 + r16;
            fb[f].u2[0] = *(const uint2*)(&Bn[buf][bn * KST + g * 8]);
            fb[f].u2[1] = *(const uint2*)(&Bn[buf][bn * KST + g * 8 + 4]);
        }
        __builtin_amdgcn_s_setprio(1);
        #pragma unroll
        for (int fi = 0; fi < 4; ++fi)
            #pragma unroll
            for (int fj = 0; fj < 4; ++fj)
                acc[fi][fj] = __builtin_amdgcn_mfma_f32_16x16x32_bf16(fa[fi].v, fb[fj].v, acc[fi][fj], 0, 0, 0);
        __builtin_amdgcn_s_setprio(0);
        if (kt < 15) stage(kt + 1, buf ^ 1);   // pack+write late (post-MFMA)
    }

    #pragma unroll
    for (int fi = 0; fi < 4; ++fi)
        #pragma unroll
        for (int fj = 0; fj < 4; ++fj) {
            const int n = nb + wc + fj * 16 + r16;
            #pragma unroll
            for (int q = 0; q < 4; ++q) {
                const int j = jb + wr + fi * 16 + g * 4 + q;
                out[(size_t)(b * 1024 + 512 + j) * NPIX + n] = acc[fi][fj][q];
            }
        }
}

extern "C" void kernel_launch(void* const* d_in, const int* in_sizes, int n_in,
                              void* d_out, int out_size, void* d_ws, size_t ws_size,
                              hipStream_t stream) {
    const float* x1 = (const float*)d_in[0];
    const float* x2 = (const float*)d_in[1];
    float* out = (float*)d_out;
    (void)in_sizes; (void)n_in; (void)out_size; (void)d_ws; (void)ws_size;

    gemm1_energy<<<dim3(1024), dim3(256), 0, stream>>>(x1, x2, out);
    softmax_rows<<<dim3(8192), dim3(256), 0, stream>>>(out);
    gemm2_av    <<<dim3(2048), dim3(256), 0, stream>>>(x1, out);
}

// Round 10
// 244.514 us; speedup vs baseline: 2.1153x; 2.1153x over previous
//
#include <hip/hip_runtime.h>

typedef short bf16x8 __attribute__((ext_vector_type(8)));
typedef float f32x4  __attribute__((ext_vector_type(4)));
typedef unsigned int u32;
typedef unsigned short u16;

#define NBATCH 16
#define C      512
#define NPIX   4096
#define ATT_OFF ((size_t)NBATCH * 1024 * NPIX)   // 67,108,864 floats

typedef __attribute__((address_space(1))) const u32* gp_t;
typedef __attribute__((address_space(3))) u32* lp_t;

// split one f32 pair (raw bits) -> packed bf16 hi pair + bf16 lo pair
__device__ __forceinline__ void splitpair(u32 u0, u32 u1, u32& h, u32& l) {
    h = __builtin_amdgcn_perm(u1, u0, 0x07060302u);
    const u32 m0 = u0 & 0xFFFF0000u, m1 = u1 & 0xFFFF0000u;
    const float l0 = __uint_as_float(u0) - __uint_as_float(m0);
    const float l1 = __uint_as_float(u1) - __uint_as_float(m1);
    l = __builtin_amdgcn_perm(__float_as_uint(l1), __float_as_uint(l0), 0x07060302u);
}

// ---------------------------------------------------------------------------
// GEMM1: energy[b,i,j] = sum_n x1[b,i,n]*x2[b,j,n]  (split-bf16, 3 MFMA)
// 768 blocks = split-K=3 (43/43/42 BK=32 chunks), 3 blocks/CU.
// launch_bounds(256,3): unified reg cap 170/wave — fits 92 arch + 64 acc,
// NO spills (round 9's 4-block variant forced 64 arch VGPRs -> scratch).
// Single-buffer 32KB f32 LDS via global_load_lds DMA; stage(kt+1) issued
// after reads-done barrier; its vmcnt drain at the next barrier is hidden
// by the other 2 resident blocks (m114 cross-block overlap).
// ks=0 partial -> att slot; ks=1,2 parked in av region (gemm2 overwrites).
// ---------------------------------------------------------------------------
__global__ __launch_bounds__(256, 3) void gemm1_energy(
    const float* __restrict__ x1, const float* __restrict__ x2,
    float* __restrict__ out)
{
    __shared__ __align__(16) float Asm[128 * 32];
    __shared__ __align__(16) float Bsm[128 * 32];

    const int tid  = threadIdx.x;
    const int lane = tid & 63;
    const int w    = tid >> 6;
    const int wr   = (w >> 1) * 64;
    const int wc   = (w & 1) * 64;
    const int r16  = lane & 15;
    const int g    = lane >> 4;

    const int gid = (blockIdx.x & 7) * 96 + (blockIdx.x >> 3);  // XCD swizzle (768%8==0)
    const int jb  = (gid & 3) * 128;
    const int ib  = ((gid >> 2) & 3) * 128;
    const int b   = (gid >> 4) & 15;
    const int ks  = gid >> 8;            // 0..2
    const int nk  = (ks < 2) ? 43 : 42;  // 43+43+42 = 128 BK-steps
    const int ko  = ks * 43 * 32;

    // staging source pointers: issue q covers tile rows w*32+q*8 .. +8
    const int lrow  = lane >> 3;        // 0..7
    const int chunk = lane & 7;         // 16B chunk within 128B row window
    const float* srcA[4];
    const float* srcB[4];
    #pragma unroll
    for (int q = 0; q < 4; ++q) {
        const int row = w * 32 + q * 8 + lrow;
        const int sc  = (chunk ^ ((row >> 1) & 7)) * 4;   // source pre-swizzle
        srcA[q] = x1 + (size_t)(b * C + ib + row) * NPIX + ko + sc;
        srcB[q] = x2 + (size_t)(b * C + jb + row) * NPIX + ko + sc;
    }

    auto stage = [&](int kt) {            // 8 global_load_lds per thread
        #pragma unroll
        for (int q = 0; q < 4; ++q) {
            __builtin_amdgcn_global_load_lds((gp_t)(const void*)(srcA[q] + kt * 32),
                                             (lp_t)(void*)&Asm[(w * 32 + q * 8) * 32], 16, 0, 0);
            __builtin_amdgcn_global_load_lds((gp_t)(const void*)(srcB[q] + kt * 32),
                                             (lp_t)(void*)&Bsm[(w * 32 + q * 8) * 32], 16, 0, 0);
        }
    };

    const f32x4 zero4 = {0.f, 0.f, 0.f, 0.f};
    f32x4 acc[4][4];
    #pragma unroll
    for (int i = 0; i < 4; ++i)
        #pragma unroll
        for (int j = 0; j < 4; ++j) acc[i][j] = zero4;

    union B8 { bf16x8 v; u32 u[4]; };

    stage(0);

    for (int kt = 0; kt < nk; ++kt) {
        __syncthreads();                  // stage(kt) landed (drains vmcnt)

        uint4 UA[4][2], UB[4][2];
        #pragma unroll
        for (int f = 0; f < 4; ++f) {
            const int ar = wr + f * 16 + r16;
            const float* abase = &Asm[ar * 32];
            UA[f][0] = *(const uint4*)(abase + (((2 * g)     ^ ((ar >> 1) & 7)) * 4));
            UA[f][1] = *(const uint4*)(abase + (((2 * g + 1) ^ ((ar >> 1) & 7)) * 4));
            const int br = wc + f * 16 + r16;
            const float* bbase = &Bsm[br * 32];
            UB[f][0] = *(const uint4*)(bbase + (((2 * g)     ^ ((br >> 1) & 7)) * 4));
            UB[f][1] = *(const uint4*)(bbase + (((2 * g + 1) ^ ((br >> 1) & 7)) * 4));
        }

        // split BEFORE barrier#2: UA/UB die here; live set = frags + acc
        B8 ah[4], al[4], bh[4], bl[4];
        #pragma unroll
        for (int f = 0; f < 4; ++f) {
            splitpair(UA[f][0].x, UA[f][0].y, ah[f].u[0], al[f].u[0]);
            splitpair(UA[f][0].z, UA[f][0].w, ah[f].u[1], al[f].u[1]);
            splitpair(UA[f][1].x, UA[f][1].y, ah[f].u[2], al[f].u[2]);
            splitpair(UA[f][1].z, UA[f][1].w, ah[f].u[3], al[f].u[3]);
            splitpair(UB[f][0].x, UB[f][0].y, bh[f].u[0], bl[f].u[0]);
            splitpair(UB[f][0].z, UB[f][0].w, bh[f].u[1], bl[f].u[1]);
            splitpair(UB[f][1].x, UB[f][1].y, bh[f].u[2], bl[f].u[2]);
            splitpair(UB[f][1].z, UB[f][1].w, bh[f].u[3], bl[f].u[3]);
        }

        __syncthreads();                  // all waves consumed LDS
        if (kt + 1 < nk) stage(kt + 1);   // overwrite LDS; flies during MFMA

        __builtin_amdgcn_s_setprio(1);
        #pragma unroll
        for (int fi = 0; fi < 4; ++fi)
            #pragma unroll
            for (int fj = 0; fj < 4; ++fj) {
                acc[fi][fj] = __builtin_amdgcn_mfma_f32_16x16x32_bf16(ah[fi].v, bh[fj].v, acc[fi][fj], 0, 0, 0);
                acc[fi][fj] = __builtin_amdgcn_mfma_f32_16x16x32_bf16(ah[fi].v, bl[fj].v, acc[fi][fj], 0, 0, 0);
                acc[fi][fj] = __builtin_amdgcn_mfma_f32_16x16x32_bf16(al[fi].v, bh[fj].v, acc[fi][fj], 0, 0, 0);
            }
        __builtin_amdgcn_s_setprio(0);
    }

    // partial energies: ks=0 -> att slot; ks=1,2 -> park in av region
    float* dst = (ks == 0)
        ? (out + ATT_OFF + (size_t)b * C * C)
        : (out + (size_t)(b * 1024 + 512) * NPIX + (size_t)(ks - 1) * C * C);
    #pragma unroll
    for (int fi = 0; fi < 4; ++fi)
        #pragma unroll
        for (int fj = 0; fj < 4; ++fj) {
            const int j = jb + wc + fj * 16 + r16;
            #pragma unroll
            for (int q = 0; q < 4; ++q) {
                const int i = ib + wr + fi * 16 + g * 4 + q;
                dst[(size_t)i * C + j] = acc[fi][fj][q];
            }
        }
}

// ---------------------------------------------------------------------------
// Softmax over last dim (512): sums the 3 split-K partials, softmaxes,
// writes final attention into the att slot.
// ---------------------------------------------------------------------------
__global__ __launch_bounds__(256) void softmax_rows(float* __restrict__ out)
{
    const int bi = blockIdx.x;          // b*512 + i
    const int b  = bi >> 9;
    const int i  = bi & 511;
    float* p        = out + ATT_OFF + (size_t)bi * C;
    const float* pk = out + (size_t)(b * 1024 + 512) * NPIX + (size_t)i * C;

    const int t = threadIdx.x;
    const int lane = t & 63, wid = t >> 6;
    __shared__ float red[8];

    float a = p[t]       + pk[t]       + pk[C * C + t];
    float c = p[t + 256] + pk[t + 256] + pk[C * C + t + 256];
    float m = fmaxf(a, c);
    #pragma unroll
    for (int o = 32; o; o >>= 1) m = fmaxf(m, __shfl_xor(m, o));
    if (lane == 0) red[wid] = m;
    __syncthreads();
    m = fmaxf(fmaxf(red[0], red[1]), fmaxf(red[2], red[3]));

    float e0 = __expf(a - m), e1 = __expf(c - m);
    float s = e0 + e1;
    #pragma unroll
    for (int o = 32; o; o >>= 1) s += __shfl_xor(s, o);
    if (lane == 0) red[4 + wid] = s;
    __syncthreads();
    s = (red[4] + red[5]) + (red[6] + red[7]);
    const float inv = 1.0f / s;
    p[t]       = e0 * inv;
    p[t + 256] = e1 * inv;
}

// ---------------------------------------------------------------------------
// GEMM2: av[b,j,n] = sum_k att[b,k,j] * x1[b,k,n]   (TT, K=512, bf16 MFMA)
// Deferred pack (T14). jt fastest in gid so the 4 blocks sharing an x1
// n-panel are dispatch-adjacent on the same XCD -> L2 absorbs re-reads.
// jt==0 blocks also copy their staged x1 f32 tile to out channels [0,512).
// ---------------------------------------------------------------------------
#define KST 36   // u16 stride per LDS row (32 + 4 pad)

__global__ __launch_bounds__(256, 3) void gemm2_av(
    const float* __restrict__ x1, float* __restrict__ out)
{
    __shared__ __align__(16) u16 Aj[2][128 * KST];  // att^T tile: row j, k 0..31
    __shared__ __align__(16) u16 Bn[2][128 * KST];  // x1^T tile: row n, k 0..31

    const float* att = out + ATT_OFF;
    const int tid  = threadIdx.x;
    const int lane = tid & 63;
    const int wid  = tid >> 6;
    const int wr   = (wid >> 1) * 64;   // j
    const int wc   = (wid & 1) * 64;    // n
    const int r16  = lane & 15;
    const int g    = lane >> 4;

    const int gid = (blockIdx.x & 7) * 256 + (blockIdx.x >> 3);  // XCD swizzle
    const int jt  = gid & 3;            // fastest: same-panel blocks adjacent
    const int nt  = (gid >> 2) & 31;
    const int b   = gid >> 7;
    const int jb  = jt * 128;
    const int nb  = nt * 128;

    const int col = (tid & 31) * 4;     // j (or n) column group staged
    const int ksr = (tid >> 5) * 4;     // 4 k's per thread per tile

    const float* ap0 = att + (size_t)b * C * C    + (size_t)ksr * C    + jb + col;
    const float* bp0 = x1  + (size_t)b * C * NPIX + (size_t)ksr * NPIX + nb + col;
    float* cpy = out + (size_t)(b * 1024 + ksr) * NPIX + nb + col;

    f32x4 La[4], Lb[4];

    auto loadk = [&](int kt) {
        #pragma unroll
        for (int i = 0; i < 4; ++i) {
            La[i] = *(const f32x4*)(ap0 + (size_t)(kt * 32 + i) * C);
            Lb[i] = *(const f32x4*)(bp0 + (size_t)(kt * 32 + i) * NPIX);
        }
    };

    auto stage = [&](int kt, int buf) {
        u32 sa[8], sb[8];
        #pragma unroll
        for (int jj = 0; jj < 4; ++jj) {
            sa[jj * 2]     = __builtin_amdgcn_perm(__float_as_uint(La[1][jj]), __float_as_uint(La[0][jj]), 0x07060302u);
            sa[jj * 2 + 1] = __builtin_amdgcn_perm(__float_as_uint(La[3][jj]), __float_as_uint(La[2][jj]), 0x07060302u);
            sb[jj * 2]     = __builtin_amdgcn_perm(__float_as_uint(Lb[1][jj]), __float_as_uint(Lb[0][jj]), 0x07060302u);
            sb[jj * 2 + 1] = __builtin_amdgcn_perm(__float_as_uint(Lb[3][jj]), __float_as_uint(Lb[2][jj]), 0x07060302u);
        }
        #pragma unroll
        for (int jj = 0; jj < 4; ++jj) {
            *(uint2*)((char*)Aj[buf] + ((col + jj) * KST + ksr) * 2) = make_uint2(sa[jj * 2], sa[jj * 2 + 1]);
            *(uint2*)((char*)Bn[buf] + ((col + jj) * KST + ksr) * 2) = make_uint2(sb[jj * 2], sb[jj * 2 + 1]);
        }
        if (jt == 0) {                  // fused x1 -> out copy
            #pragma unroll
            for (int i = 0; i < 4; ++i)
                *(f32x4*)(cpy + (size_t)(kt * 32 + i) * NPIX) = Lb[i];
        }
    };

    const f32x4 zero4 = {0.f, 0.f, 0.f, 0.f};
    f32x4 acc[4][4];
    #pragma unroll
    for (int i = 0; i < 4; ++i)
        #pragma unroll
        for (int j = 0; j < 4; ++j) acc[i][j] = zero4;

    loadk(0);
    stage(0, 0);

    for (int kt = 0; kt < 16; ++kt) {
        if (kt < 15) loadk(kt + 1);     // raw loads issued early (T14)
        __syncthreads();
        const int buf = kt & 1;

        union { bf16x8 v; uint2 u2[2]; } fa[4], fb[4];
        #pragma unroll
        for (int f = 0; f < 4; ++f) {
            const int aj = wr + f * 16 + r16;
            fa[f].u2[0] = *(const uint2*)(&Aj[buf][aj * KST + g * 8]);
            fa[f].u2[1] = *(const uint2*)(&Aj[buf][aj * KST + g * 8 + 4]);
            const int bn = wc + f * 16 + r16;
            fb[f].u2[0] = *(const uint2*)(&Bn[buf][bn * KST + g * 8]);
            fb[f].u2[1] = *(const uint2*)(&Bn[buf][bn * KST + g * 8 + 4]);
        }
        __builtin_amdgcn_s_setprio(1);
        #pragma unroll
        for (int fi = 0; fi < 4; ++fi)
            #pragma unroll
            for (int fj = 0; fj < 4; ++fj)
                acc[fi][fj] = __builtin_amdgcn_mfma_f32_16x16x32_bf16(fa[fi].v, fb[fj].v, acc[fi][fj], 0, 0, 0);
        __builtin_amdgcn_s_setprio(0);
        if (kt < 15) stage(kt + 1, buf ^ 1);   // pack+write late (post-MFMA)
    }

    #pragma unroll
    for (int fi = 0; fi < 4; ++fi)
        #pragma unroll
        for (int fj = 0; fj < 4; ++fj) {
            const int n = nb + wc + fj * 16 + r16;
            #pragma unroll
            for (int q = 0; q < 4; ++q) {
                const int j = jb + wr + fi * 16 + g * 4 + q;
                out[(size_t)(b * 1024 + 512 + j) * NPIX + n] = acc[fi][fj][q];
            }
        }
}

extern "C" void kernel_launch(void* const* d_in, const int* in_sizes, int n_in,
                              void* d_out, int out_size, void* d_ws, size_t ws_size,
                              hipStream_t stream) {
    const float* x1 = (const float*)d_in[0];
    const float* x2 = (const float*)d_in[1];
    float* out = (float*)d_out;
    (void)in_sizes; (void)n_in; (void)out_size; (void)d_ws; (void)ws_size;

    gemm1_energy<<<dim3(768),  dim3(256), 0, stream>>>(x1, x2, out);
    softmax_rows<<<dim3(8192), dim3(256), 0, stream>>>(out);
    gemm2_av    <<<dim3(2048), dim3(256), 0, stream>>>(x1, out);
}

// Round 11
// 237.147 us; speedup vs baseline: 2.1810x; 1.0311x over previous
//
#include <hip/hip_runtime.h>

typedef short bf16x8 __attribute__((ext_vector_type(8)));
typedef float f32x4  __attribute__((ext_vector_type(4)));
typedef unsigned int u32;
typedef unsigned short u16;

#define NBATCH 16
#define C      512
#define NPIX   4096
#define ATT_OFF ((size_t)NBATCH * 1024 * NPIX)   // 67,108,864 floats

typedef __attribute__((address_space(1))) const u32* gp_t;
typedef __attribute__((address_space(3))) u32* lp_t;

// split one f32 pair (raw bits) -> packed bf16 hi pair + bf16 lo pair
__device__ __forceinline__ void splitpair(u32 u0, u32 u1, u32& h, u32& l) {
    h = __builtin_amdgcn_perm(u1, u0, 0x07060302u);
    const u32 m0 = u0 & 0xFFFF0000u, m1 = u1 & 0xFFFF0000u;
    const float l0 = __uint_as_float(u0) - __uint_as_float(m0);
    const float l1 = __uint_as_float(u1) - __uint_as_float(m1);
    l = __builtin_amdgcn_perm(__float_as_uint(l1), __float_as_uint(l0), 0x07060302u);
}

// ---------------------------------------------------------------------------
// GEMM1 (r4 structure — best measured): energy[b,i,j] = sum_n x1*x2.
// 512 blocks (2/CU), block split-K=2, DMA staging, prefetch distance 2,
// counted vmcnt (never drained mid-loop), raw s_barrier pair per kt.
// ks=0 partial -> att slot; ks=1 partial -> park (front of av region).
// ---------------------------------------------------------------------------
__global__ __launch_bounds__(256, 2) void gemm1_energy(
    const float* __restrict__ x1, const float* __restrict__ x2,
    float* __restrict__ out)
{
    __shared__ __align__(16) float Asm[2][128 * 32];
    __shared__ __align__(16) float Bsm[2][128 * 32];

    const int tid  = threadIdx.x;
    const int lane = tid & 63;
    const int w    = tid >> 6;
    const int wr   = (w >> 1) * 64;
    const int wc   = (w & 1) * 64;
    const int r16  = lane & 15;
    const int g    = lane >> 4;

    const int gid = (blockIdx.x & 7) * 64 + (blockIdx.x >> 3);  // XCD swizzle
    const int b   = gid >> 5;
    const int ib  = ((gid >> 3) & 3) * 128;
    const int jb  = ((gid >> 1) & 3) * 128;
    const int ks  = gid & 1;
    const int ko  = ks * 2048;

    const int lrow  = lane >> 3;        // 0..7
    const int chunk = lane & 7;         // 16B chunk within 128B row window
    const float* srcA[4];
    const float* srcB[4];
    #pragma unroll
    for (int q = 0; q < 4; ++q) {
        const int row = w * 32 + q * 8 + lrow;
        const int sc  = (chunk ^ ((row >> 1) & 7)) * 4;   // source pre-swizzle
        srcA[q] = x1 + (size_t)(b * C + ib + row) * NPIX + ko + sc;
        srcB[q] = x2 + (size_t)(b * C + jb + row) * NPIX + ko + sc;
    }

    auto stage = [&](int kt, int buf) {   // 8 global_load_lds per thread
        #pragma unroll
        for (int q = 0; q < 4; ++q) {
            __builtin_amdgcn_global_load_lds((gp_t)(const void*)(srcA[q] + kt * 32),
                                             (lp_t)(void*)&Asm[buf][(w * 32 + q * 8) * 32], 16, 0, 0);
            __builtin_amdgcn_global_load_lds((gp_t)(const void*)(srcB[q] + kt * 32),
                                             (lp_t)(void*)&Bsm[buf][(w * 32 + q * 8) * 32], 16, 0, 0);
        }
    };

    const f32x4 zero4 = {0.f, 0.f, 0.f, 0.f};
    f32x4 acc[4][4];
    #pragma unroll
    for (int i = 0; i < 4; ++i)
        #pragma unroll
        for (int j = 0; j < 4; ++j) acc[i][j] = zero4;

    union B8 { bf16x8 v; u32 u[4]; };

    stage(0, 0);
    stage(1, 1);                          // 16 loads/thread in flight

    for (int kt = 0; kt < 64; ++kt) {
        const int buf = kt & 1;

        if (kt < 63) asm volatile("s_waitcnt vmcnt(8)" ::: "memory");
        else         asm volatile("s_waitcnt vmcnt(0)" ::: "memory");
        __builtin_amdgcn_s_barrier();     // ALL waves' loads for buf landed

        uint4 UA[4][2], UB[4][2];
        #pragma unroll
        for (int f = 0; f < 4; ++f) {
            const int ar = wr + f * 16 + r16;
            const float* abase = &Asm[buf][ar * 32];
            UA[f][0] = *(const uint4*)(abase + (((2 * g)     ^ ((ar >> 1) & 7)) * 4));
            UA[f][1] = *(const uint4*)(abase + (((2 * g + 1) ^ ((ar >> 1) & 7)) * 4));
            const int br = wc + f * 16 + r16;
            const float* bbase = &Bsm[buf][br * 32];
            UB[f][0] = *(const uint4*)(bbase + (((2 * g)     ^ ((br >> 1) & 7)) * 4));
            UB[f][1] = *(const uint4*)(bbase + (((2 * g + 1) ^ ((br >> 1) & 7)) * 4));
        }
        asm volatile("s_waitcnt lgkmcnt(0)" ::: "memory");  // reads in regs
        __builtin_amdgcn_sched_barrier(0);                  // rule-18 fence
        __builtin_amdgcn_s_barrier();     // all waves done reading buf

        if (kt + 2 < 64) stage(kt + 2, buf);  // overwrite buf; lands by kt+2

        B8 ah[4], al[4], bh[4], bl[4];
        #pragma unroll
        for (int f = 0; f < 4; ++f) {
            splitpair(UA[f][0].x, UA[f][0].y, ah[f].u[0], al[f].u[0]);
            splitpair(UA[f][0].z, UA[f][0].w, ah[f].u[1], al[f].u[1]);
            splitpair(UA[f][1].x, UA[f][1].y, ah[f].u[2], al[f].u[2]);
            splitpair(UA[f][1].z, UA[f][1].w, ah[f].u[3], al[f].u[3]);
            splitpair(UB[f][0].x, UB[f][0].y, bh[f].u[0], bl[f].u[0]);
            splitpair(UB[f][0].z, UB[f][0].w, bh[f].u[1], bl[f].u[1]);
            splitpair(UB[f][1].x, UB[f][1].y, bh[f].u[2], bl[f].u[2]);
            splitpair(UB[f][1].z, UB[f][1].w, bh[f].u[3], bl[f].u[3]);
        }

        __builtin_amdgcn_s_setprio(1);
        #pragma unroll
        for (int fi = 0; fi < 4; ++fi)
            #pragma unroll
            for (int fj = 0; fj < 4; ++fj) {
                acc[fi][fj] = __builtin_amdgcn_mfma_f32_16x16x32_bf16(ah[fi].v, bh[fj].v, acc[fi][fj], 0, 0, 0);
                acc[fi][fj] = __builtin_amdgcn_mfma_f32_16x16x32_bf16(ah[fi].v, bl[fj].v, acc[fi][fj], 0, 0, 0);
                acc[fi][fj] = __builtin_amdgcn_mfma_f32_16x16x32_bf16(al[fi].v, bh[fj].v, acc[fi][fj], 0, 0, 0);
            }
        __builtin_amdgcn_s_setprio(0);
    }

    float* dst = (ks == 0) ? (out + ATT_OFF + (size_t)b * C * C)
                           : (out + (size_t)(b * 1024 + 512) * NPIX);
    #pragma unroll
    for (int fi = 0; fi < 4; ++fi)
        #pragma unroll
        for (int fj = 0; fj < 4; ++fj) {
            const int j = jb + wc + fj * 16 + r16;
            #pragma unroll
            for (int q = 0; q < 4; ++q) {
                const int i = ib + wr + fi * 16 + g * 4 + q;
                dst[(size_t)i * C + j] = acc[fi][fj][q];
            }
        }
}

// ---------------------------------------------------------------------------
// Softmax over last dim (512): adds the two split-K partials, softmaxes,
// writes final attention into the att slot.
// ---------------------------------------------------------------------------
__global__ __launch_bounds__(256) void softmax_rows(float* __restrict__ out)
{
    const int bi = blockIdx.x;          // b*512 + i
    const int b  = bi >> 9;
    const int i  = bi & 511;
    float* p        = out + ATT_OFF + (size_t)bi * C;
    const float* pk = out + (size_t)(b * 1024 + 512) * NPIX + (size_t)i * C;

    const int t = threadIdx.x;
    const int lane = t & 63, wid = t >> 6;
    __shared__ float red[8];

    float a = p[t] + pk[t];
    float c = p[t + 256] + pk[t + 256];
    float m = fmaxf(a, c);
    #pragma unroll
    for (int o = 32; o; o >>= 1) m = fmaxf(m, __shfl_xor(m, o));
    if (lane == 0) red[wid] = m;
    __syncthreads();
    m = fmaxf(fmaxf(red[0], red[1]), fmaxf(red[2], red[3]));

    float e0 = __expf(a - m), e1 = __expf(c - m);
    float s = e0 + e1;
    #pragma unroll
    for (int o = 32; o; o >>= 1) s += __shfl_xor(s, o);
    if (lane == 0) red[4 + wid] = s;
    __syncthreads();
    s = (red[4] + red[5]) + (red[6] + red[7]);
    const float inv = 1.0f / s;
    p[t]       = e0 * inv;
    p[t + 256] = e1 * inv;
}

// ---------------------------------------------------------------------------
// GEMM2: av[b,j,n] = sum_k att[b,k,j] * x1[b,k,n]   (TT, K=512, bf16 MFMA)
// Deferred pack (T14). x1->out copy LOAD-BALANCED: each of the 4 jt-sharers
// of an (b,nt) x1 panel copies its own k-quarter ((kt>>2)==jt) — was jt==0
// only (4x copy work on 1/4 of blocks -> tail serialization).
// ---------------------------------------------------------------------------
#define KST 36   // u16 stride per LDS row (32 + 4 pad)

__global__ __launch_bounds__(256, 3) void gemm2_av(
    const float* __restrict__ x1, float* __restrict__ out)
{
    __shared__ __align__(16) u16 Aj[2][128 * KST];  // att^T tile: row j, k 0..31
    __shared__ __align__(16) u16 Bn[2][128 * KST];  // x1^T tile: row n, k 0..31

    const float* att = out + ATT_OFF;
    const int tid  = threadIdx.x;
    const int lane = tid & 63;
    const int wid  = tid >> 6;
    const int wr   = (wid >> 1) * 64;   // j
    const int wc   = (wid & 1) * 64;    // n
    const int r16  = lane & 15;
    const int g    = lane >> 4;

    const int gid = (blockIdx.x & 7) * 256 + (blockIdx.x >> 3);  // XCD swizzle
    const int jt  = gid & 3;            // fastest: same-panel blocks adjacent
    const int nt  = (gid >> 2) & 31;
    const int b   = gid >> 7;
    const int jb  = jt * 128;
    const int nb  = nt * 128;

    const int col = (tid & 31) * 4;     // j (or n) column group staged
    const int ksr = (tid >> 5) * 4;     // 4 k's per thread per tile

    const float* ap0 = att + (size_t)b * C * C    + (size_t)ksr * C    + jb + col;
    const float* bp0 = x1  + (size_t)b * C * NPIX + (size_t)ksr * NPIX + nb + col;
    float* cpy = out + (size_t)(b * 1024 + ksr) * NPIX + nb + col;

    f32x4 La[4], Lb[4];

    auto loadk = [&](int kt) {
        #pragma unroll
        for (int i = 0; i < 4; ++i) {
            La[i] = *(const f32x4*)(ap0 + (size_t)(kt * 32 + i) * C);
            Lb[i] = *(const f32x4*)(bp0 + (size_t)(kt * 32 + i) * NPIX);
        }
    };

    auto stage = [&](int kt, int buf) {
        u32 sa[8], sb[8];
        #pragma unroll
        for (int jj = 0; jj < 4; ++jj) {
            sa[jj * 2]     = __builtin_amdgcn_perm(__float_as_uint(La[1][jj]), __float_as_uint(La[0][jj]), 0x07060302u);
            sa[jj * 2 + 1] = __builtin_amdgcn_perm(__float_as_uint(La[3][jj]), __float_as_uint(La[2][jj]), 0x07060302u);
            sb[jj * 2]     = __builtin_amdgcn_perm(__float_as_uint(Lb[1][jj]), __float_as_uint(Lb[0][jj]), 0x07060302u);
            sb[jj * 2 + 1] = __builtin_amdgcn_perm(__float_as_uint(Lb[3][jj]), __float_as_uint(Lb[2][jj]), 0x07060302u);
        }
        #pragma unroll
        for (int jj = 0; jj < 4; ++jj) {
            *(uint2*)((char*)Aj[buf] + ((col + jj) * KST + ksr) * 2) = make_uint2(sa[jj * 2], sa[jj * 2 + 1]);
            *(uint2*)((char*)Bn[buf] + ((col + jj) * KST + ksr) * 2) = make_uint2(sb[jj * 2], sb[jj * 2 + 1]);
        }
        if ((kt >> 2) == jt) {          // balanced fused x1 -> out copy
            #pragma unroll
            for (int i = 0; i < 4; ++i)
                *(f32x4*)(cpy + (size_t)(kt * 32 + i) * NPIX) = Lb[i];
        }
    };

    const f32x4 zero4 = {0.f, 0.f, 0.f, 0.f};
    f32x4 acc[4][4];
    #pragma unroll
    for (int i = 0; i < 4; ++i)
        #pragma unroll
        for (int j = 0; j < 4; ++j) acc[i][j] = zero4;

    loadk(0);
    stage(0, 0);

    for (int kt = 0; kt < 16; ++kt) {
        if (kt < 15) loadk(kt + 1);     // raw loads issued early (T14)
        __syncthreads();
        const int buf = kt & 1;

        union { bf16x8 v; uint2 u2[2]; } fa[4], fb[4];
        #pragma unroll
        for (int f = 0; f < 4; ++f) {
            const int aj = wr + f * 16 + r16;
            fa[f].u2[0] = *(const uint2*)(&Aj[buf][aj * KST + g * 8]);
            fa[f].u2[1] = *(const uint2*)(&Aj[buf][aj * KST + g * 8 + 4]);
            const int bn = wc + f * 16 + r16;
            fb[f].u2[0] = *(const uint2*)(&Bn[buf][bn * KST + g * 8]);
            fb[f].u2[1] = *(const uint2*)(&Bn[buf][bn * KST + g * 8 + 4]);
        }
        __builtin_amdgcn_s_setprio(1);
        #pragma unroll
        for (int fi = 0; fi < 4; ++fi)
            #pragma unroll
            for (int fj = 0; fj < 4; ++fj)
                acc[fi][fj] = __builtin_amdgcn_mfma_f32_16x16x32_bf16(fa[fi].v, fb[fj].v, acc[fi][fj], 0, 0, 0);
        __builtin_amdgcn_s_setprio(0);
        if (kt < 15) stage(kt + 1, buf ^ 1);   // pack+write late (post-MFMA)
    }

    #pragma unroll
    for (int fi = 0; fi < 4; ++fi)
        #pragma unroll
        for (int fj = 0; fj < 4; ++fj) {
            const int n = nb + wc + fj * 16 + r16;
            #pragma unroll
            for (int q = 0; q < 4; ++q) {
                const int j = jb + wr + fi * 16 + g * 4 + q;
                out[(size_t)(b * 1024 + 512 + j) * NPIX + n] = acc[fi][fj][q];
            }
        }
}

extern "C" void kernel_launch(void* const* d_in, const int* in_sizes, int n_in,
                              void* d_out, int out_size, void* d_ws, size_t ws_size,
                              hipStream_t stream) {
    const float* x1 = (const float*)d_in[0];
    const float* x2 = (const float*)d_in[1];
    float* out = (float*)d_out;
    (void)in_sizes; (void)n_in; (void)out_size; (void)d_ws; (void)ws_size;

    gemm1_energy<<<dim3(512),  dim3(256), 0, stream>>>(x1, x2, out);
    softmax_rows<<<dim3(8192), dim3(256), 0, stream>>>(out);
    gemm2_av    <<<dim3(2048), dim3(256), 0, stream>>>(x1, out);
}